// Round 5
// baseline (259.588 us; speedup 1.0000x reference)
//
#include <hip/hip_runtime.h>
#include <math.h>

#define Vn 5
#define Cn 32
#define Hn 384
#define Wn 384
#define Dn 4
#define Gn 8
#define HWn (Hn*Wn)   // 147456

typedef _Float16 h2 __attribute__((ext_vector_type(2)));
typedef float    f2 __attribute__((ext_vector_type(2)));

__device__ __forceinline__ float fdot2h(h2 a, h2 b, float c){
#if __has_builtin(__builtin_amdgcn_fdot2)
    return __builtin_amdgcn_fdot2(a, b, c, false);
#else
    return (float)a.x*(float)b.x + (float)a.y*(float)b.y + c;
#endif
}
__device__ __forceinline__ unsigned int packh2(float a, float b){  // accurate pack (RNE)
    h2 h;
    h.x = (_Float16)a;
    h.y = (_Float16)b;
    return __builtin_bit_cast(unsigned int, h);
}
// packed fp32 helpers -> v_pk_fma_f32 / v_pk_max_f32 (exact same fma math per lane)
__device__ __forceinline__ f2 fma2(f2 a, f2 b, f2 c){ return __builtin_elementwise_fma(a, b, c); }
__device__ __forceinline__ f2 max2(f2 a, f2 b){ return __builtin_elementwise_max(a, b); }
__device__ __forceinline__ f2 splat2(float x){ f2 r; r.x = x; r.y = x; return r; }

// ---------- small 3x3 helpers (device) ----------
__device__ __forceinline__ void inv3(const float* m, float* o){
    float a=m[0],b=m[1],c=m[2],d=m[3],e=m[4],f=m[5],g=m[6],h=m[7],i=m[8];
    float A =  e*i - f*h;
    float B = -(d*i - f*g);
    float C =  d*h - e*g;
    float det = a*A + b*B + c*C;
    float r = 1.f/det;
    o[0] = A*r;            o[1] = -(b*i - c*h)*r;  o[2] =  (b*f - c*e)*r;
    o[3] = B*r;            o[4] =  (a*i - c*g)*r;  o[5] = -(a*f - c*d)*r;
    o[6] = C*r;            o[7] = -(a*h - b*g)*r;  o[8] =  (a*e - b*d)*r;
}
__device__ __forceinline__ void mm3(const float* a, const float* b, float* o){
    #pragma unroll
    for (int r=0;r<3;r++)
        #pragma unroll
        for (int c=0;c<3;c++)
            o[r*3+c] = a[r*3+0]*b[0*3+c] + a[r*3+1]*b[1*3+c] + a[r*3+2]*b[2*3+c];
}
__device__ __forceinline__ void mv3(const float* a, const float* v, float* o){
    #pragma unroll
    for (int r=0;r<3;r++)
        o[r] = a[r*3+0]*v[0] + a[r*3+1]*v[1] + a[r*3+2]*v[2];
}

// ---------- transpose+convert (C,H,W) fp32 -> (H*W, C) f16 ----------
// LDS-free: each thread owns 4 consecutive pixels; float4 loads fully
// coalesced, packs in registers, 16B stores covering a contiguous 16KB/wave.
__global__ __launch_bounds__(256)
void transpose_kernel(const float* __restrict__ feat, unsigned short* __restrict__ featT){
    const int s  = blockIdx.y;                              // 0..3 -> view s+1
    const int p0 = blockIdx.x * 1024 + threadIdx.x * 4;     // 4 consecutive pixels
    const float* src = feat + (size_t)(s+1)*Cn*HWn + p0;
    unsigned int outw[4][16];
    #pragma unroll
    for (int c=0; c<Cn; c+=2){
        const float4 a = *(const float4*)(src + (size_t)c*HWn);
        const float4 b = *(const float4*)(src + (size_t)(c+1)*HWn);
        outw[0][c>>1] = packh2(a.x, b.x);
        outw[1][c>>1] = packh2(a.y, b.y);
        outw[2][c>>1] = packh2(a.z, b.z);
        outw[3][c>>1] = packh2(a.w, b.w);
    }
    uint4* dst = (uint4*)(featT + ((size_t)s*HWn + p0)*Cn);
    #pragma unroll
    for (int p=0;p<4;p++){
        #pragma unroll
        for (int q=0;q<4;q++){
            uint4 o;
            o.x = outw[p][4*q+0];
            o.y = outw[p][4*q+1];
            o.z = outw[p][4*q+2];
            o.w = outw[p][4*q+3];
            dst[p*4+q] = o;
        }
    }
}

// quarter-tap: this lane loads ONE 16B quarter (channels 8q..8q+7) of the
// 64B tap record; the pixel's 4 quarter-lanes cover the record coalesced.
// Per-group dot chain identical to the old DOTG -> bit-identical sims.
__device__ __forceinline__ void qtap(const unsigned short* __restrict__ vb,
                                     int xc, int yc, float w,
                                     const h2* r2q, float& sg0, float& sg1)
{
    if (w != 0.f){
        const uint4 u = *(const uint4*)(vb + ((size_t)yc*Wn + xc)*Cn);
        const h2 a0 = __builtin_bit_cast(h2, u.x);
        const h2 a1 = __builtin_bit_cast(h2, u.y);
        const h2 a2 = __builtin_bit_cast(h2, u.z);
        const h2 a3 = __builtin_bit_cast(h2, u.w);
        sg0 = fmaf(w, fdot2h(a0, r2q[0], fdot2h(a1, r2q[1], 0.f)), sg0);
        sg1 = fmaf(w, fdot2h(a2, r2q[2], fdot2h(a3, r2q[3], 0.f)), sg1);
    }
}

// ---------- fused main kernel ----------
// R5: thread = (pixel, channel-quarter). t = pixLocal*4 + q; wave = 16
// consecutive pixels x 4 quarters. R4 POST-MORTEM: occupancy 28->43% with
// zero speedup => gather TAG-THROUGHPUT bound (~0.8 line-transactions/cy/CU,
// at the ~1/cy limit). Fix = coalesce: 4 quarter-lanes cover one 64B tap
// record; a wave-instr touches ~8-16 sequential cachelines (16 adjacent
// records) instead of ~64 scattered ones -> 4-8x fewer tag transactions.
// Each thread loops 4 views x 4 depths x 4 guarded taps accumulating its 2
// groups, then a 2-stage shfl_xor butterfly transpose (conditional swap,
// compile-time indices only) turns quarter-lanes into view-lanes; MLP and
// reductions identical to R3 (bit-identical chains).
// NOTE: all register arrays accessed ONLY with compile-time indices (SROA).
__global__ __launch_bounds__(256, 2)
void gbinet_kernel(const float* __restrict__ feat,
                   const float* __restrict__ depths,
                   const float* __restrict__ Kin,
                   const float* __restrict__ Ein,
                   const float* __restrict__ w0, const float* __restrict__ b0,
                   const float* __restrict__ w1, const float* __restrict__ b1,
                   const float* __restrict__ w2, const float* __restrict__ b2,
                   const unsigned short* __restrict__ featT,
                   float* __restrict__ out)
{
    __shared__ float sW0[128], sW1[128], sB0[16], sB1[8], sW2[8], sB2s[1];
    __shared__ float sM[48];            // per source view: A[9] + c[3]
    __shared__ float sRef[64*33];       // 64 pixels x 32 ref channels (pad 33)
    __shared__ float sDep[4*65];        // 4 depth planes x 64 pixels (pad 65)
    __shared__ float sOut[64*33];       // 64 pixels x 32 outputs (pad 33)
    const int t = threadIdx.x;
    if (t < 128){ sW0[t] = w0[t]; sW1[t] = w1[t]; }
    if (t < 16) sB0[t] = b0[t];
    if (t < 8){ sB1[t] = b1[t]; sW2[t] = w2[t]; }

    // XCD swizzle: round-robin dispatch -> each XCD gets a contiguous 288-block
    // (48-row) strip; featT tap neighborhoods stay in its private 4MB L2.
    const int bid = blockIdx.x;
    const int sid = (bid & 7) * (HWn/64/8) + (bid >> 3);
    const int blockBase = sid * 64;

    // cooperative coalesced stage of ref (view0 fp32) and depths for 64 pixels
    {
        const float* srcR = feat + blockBase;
        #pragma unroll
        for (int k=0;k<8;k++){
            const int i  = k*256 + t;
            const int c  = i >> 6;
            const int px = i & 63;
            sRef[px*33 + c] = srcR[(size_t)c*HWn + px];
        }
        const int dp = t >> 6;          // 0..3
        const int px = t & 63;
        sDep[dp*65 + px] = depths[(size_t)dp*HWn + blockBase + px];
    }

    // Projection-chain setup, 4-way lane-parallel (one lane per source view).
    if (t < 4){
        float K0inv[9]; inv3(Kin, K0inv);
        float R0[9], t0[3];
        #pragma unroll
        for (int r=0;r<3;r++){
            #pragma unroll
            for (int c=0;c<3;c++) R0[r*3+c] = Ein[r*4+c];
            t0[r] = Ein[r*4+3];
        }
        float R0inv[9]; inv3(R0, R0inv);
        float M0[9]; mm3(R0inv, K0inv, M0);
        float Rt0[3]; mv3(R0inv, t0, Rt0);
        const int sv = t + 1;
        const float* Ks = Kin + sv*9;
        const float* Es = Ein + sv*12;
        float Rs[9], ts[3];
        #pragma unroll
        for (int r=0;r<3;r++){
            #pragma unroll
            for (int c=0;c<3;c++) Rs[r*3+c] = Es[r*4+c];
            ts[r] = Es[r*4+3];
        }
        float T1[9]; mm3(Rs, M0, T1);
        float A9[9]; mm3(Ks, T1, A9);
        float Rr[3]; mv3(Rs, Rt0, Rr);
        float tv[3] = { ts[0]-Rr[0], ts[1]-Rr[1], ts[2]-Rr[2] };
        float cv[3]; mv3(Ks, tv, cv);
        float* dm = &sM[t*12];
        #pragma unroll
        for (int i=0;i<9;i++) dm[i] = A9[i];
        #pragma unroll
        for (int i=0;i<3;i++) dm[9+i] = cv[i];
    }
    if (t == 4) sB2s[0] = b2[0];
    __syncthreads();

    const int pixLocal = t >> 2;        // 0..63
    const int q        = t & 3;         // channel-quarter (taps) / view (MLP)
    const int pix      = blockBase + pixLocal;
    const float xg = (float)(pix % Wn) + 0.5f;
    const float yg = (float)(pix / Wn) + 0.5f;

    // this lane's 8 ref channels (8q..8q+7) as 4 packed half2
    h2 r2q[4];
    #pragma unroll
    for (int k=0;k<4;k++){
        r2q[k].x = (_Float16)sRef[pixLocal*33 + 8*q + 2*k];
        r2q[k].y = (_Float16)sRef[pixLocal*33 + 8*q + 2*k+1];
    }
    float dep[Dn];
    #pragma unroll
    for (int d=0;d<Dn;d++) dep[d] = sDep[d*65 + pixLocal];

    // A[v][i], i = g2*4 + d  (g2 = local group 0/1 -> global group 2q+g2)
    float A[4][8];
    #pragma unroll
    for (int v=0;v<4;v++)
        #pragma unroll
        for (int i=0;i<8;i++) A[v][i] = 0.f;

    #pragma unroll
    for (int v=0; v<4; v++){
        const float* M = &sM[v*12];
        const float bx = M[0]*xg + M[1]*yg + M[2];
        const float by = M[3]*xg + M[4]*yg + M[5];
        const float bz = M[6]*xg + M[7]*yg + M[8];
        const float cx = M[9], cy = M[10], cz = M[11];
        const unsigned short* vbase = featT + (size_t)v*HWn*Cn + q*8;
        #pragma unroll
        for (int d=0; d<Dn; d++){
            const float dd = dep[d];
            const float ux = fmaf(bx, dd, cx);
            const float uy = fmaf(by, dd, cy);
            const float uz = fmaf(bz, dd, cz) + 1e-9f;
            const float rz = 1.f/uz;
            const float px = ux*rz, py = uy*rz;
            const float x0 = floorf(px), y0 = floorf(py);
            const float wx1 = px - x0, wy1 = py - y0;
            const float wx0 = 1.f - wx1, wy0 = 1.f - wy1;
            const bool vx0 = (x0 >= 0.f)     && (x0 <= (float)(Wn-1));
            const bool vx1 = (x0 >= -1.f)    && (x0 <= (float)(Wn-2));
            const bool vy0 = (y0 >= 0.f)     && (y0 <= (float)(Hn-1));
            const bool vy1 = (y0 >= -1.f)    && (y0 <= (float)(Hn-2));
            // fold the 1/4 group-mean into the tap weights
            const float w00 = (vx0&&vy0) ? 0.25f*wx0*wy0 : 0.f;
            const float w10 = (vx1&&vy0) ? 0.25f*wx1*wy0 : 0.f;
            const float w01 = (vx0&&vy1) ? 0.25f*wx0*wy1 : 0.f;
            const float w11 = (vx1&&vy1) ? 0.25f*wx1*wy1 : 0.f;
            // clamped integer coords (always safe to load)
            const int xi0 = (int)fminf(fmaxf(x0,     0.f), (float)(Wn-1));
            const int xi1 = (int)fminf(fmaxf(x0+1.f, 0.f), (float)(Wn-1));
            const int yi0 = (int)fminf(fmaxf(y0,     0.f), (float)(Hn-1));
            const int yi1 = (int)fminf(fmaxf(y0+1.f, 0.f), (float)(Hn-1));

            float sg0 = 0.f, sg1 = 0.f;
            qtap(vbase, xi0, yi0, w00, r2q, sg0, sg1);
            qtap(vbase, xi1, yi0, w10, r2q, sg0, sg1);
            qtap(vbase, xi0, yi1, w01, r2q, sg0, sg1);
            qtap(vbase, xi1, yi1, w11, r2q, sg0, sg1);
            A[v][d]   = sg0;
            A[v][4+d] = sg1;
        }
    }

    // ---- 4x4 butterfly transpose of 8-float packets across the quarter
    // lanes: lane q held (groups 2q,2q+1) x all views; afterwards it holds
    // all 8 groups x view q. Conditional-swap keeps all indices literal.
    const bool q0b = (q & 1) != 0;
    const bool q1b = (q & 2) != 0;
    float Bp[2][2][8];                  // [v1][gp0][i] after stage 1
    #pragma unroll
    for (int i=0;i<8;i++){
        const float s0 = q0b ? A[0][i] : A[1][i];
        const float s1 = q0b ? A[2][i] : A[3][i];
        const float r0 = __shfl_xor(s0, 1);
        const float r1 = __shfl_xor(s1, 1);
        Bp[0][0][i] = q0b ? r0 : A[0][i];
        Bp[0][1][i] = q0b ? A[1][i] : r0;
        Bp[1][0][i] = q0b ? r1 : A[2][i];
        Bp[1][1][i] = q0b ? A[3][i] : r1;
    }
    float Cp[2][2][8];                  // [gp1][gp0][i], view == q now
    #pragma unroll
    for (int i=0;i<8;i++){
        #pragma unroll
        for (int g0=0; g0<2; g0++){
            const float tt = q1b ? Bp[0][g0][i] : Bp[1][g0][i];
            const float u  = __shfl_xor(tt, 2);
            Cp[0][g0][i] = q1b ? u : Bp[0][g0][i];
            Cp[1][g0][i] = q1b ? Bp[1][g0][i] : u;
        }
    }
    // accessor: sim[g][d] = Cp[g>>2][(g>>1)&1][(g&1)*4 + d]

    // pixelwise net for view q over 4 depths, two at a time via packed fp32
    // (identical fma chain -> bit-identical). max(sigmoid)==sigmoid(max logit).
    float maxlog = -3.0e38f;
    #pragma unroll
    for (int dp=0; dp<2; dp++){
        const int d0 = 2*dp, d1 = 2*dp+1;
        f2 sv[Gn];
        #pragma unroll
        for (int g=0; g<Gn; g++){
            sv[g].x = Cp[g>>2][(g>>1)&1][(g&1)*4 + d0];
            sv[g].y = Cp[g>>2][(g>>1)&1][(g&1)*4 + d1];
        }
        f2 hreg[16];
        #pragma unroll
        for (int o=0;o<16;o++){
            f2 a = splat2(sB0[o]);
            #pragma unroll
            for (int g=0; g<Gn; g++)
                a = fma2(splat2(sW0[o*Gn+g]), sv[g], a);
            hreg[o] = max2(a, splat2(0.f));
        }
        f2 lg = splat2(sB2s[0]);
        #pragma unroll
        for (int o=0;o<8;o++){
            f2 a = splat2(sB1[o]);
            #pragma unroll
            for (int i=0;i<16;i++)
                a = fma2(splat2(sW1[o*16+i]), hreg[i], a);
            lg = fma2(splat2(sW2[o]), max2(a, splat2(0.f)), lg);
        }
        maxlog = fmaxf(maxlog, fmaxf(lg.x, lg.y));
    }
    const float vw = 1.f/(1.f + __expf(-maxlog));

    // scale by vw, butterfly-reduce across the 4 view lanes (bits 0-1)
    float wsum = vw;
    wsum += __shfl_xor(wsum, 1);
    wsum += __shfl_xor(wsum, 2);
    #pragma unroll
    for (int j1=0;j1<2;j1++)
        #pragma unroll
        for (int j0=0;j0<2;j0++)
            #pragma unroll
            for (int i=0;i<8;i++){
                float vv = Cp[j1][j0][i]*vw;
                vv += __shfl_xor(vv, 1);
                vv += __shfl_xor(vv, 2);
                Cp[j1][j0][i] = vv;
            }

    if (q == 0){
        const float invw = 1.f/wsum;
        #pragma unroll
        for (int g=0;g<Gn;g++)
            #pragma unroll
            for (int d=0;d<Dn;d++)
                sOut[pixLocal*33 + g*Dn + d] = Cp[g>>2][(g>>1)&1][(g&1)*4+d]*invw;
    }
    __syncthreads();

    // coalesced write-out: 32 planes x 64 pixels
    float* oBase = out + blockBase;
    #pragma unroll
    for (int k=0;k<8;k++){
        const int e     = k*256 + t;
        const int plane = e >> 6;
        const int pixel = e & 63;
        oBase[(size_t)plane*HWn + pixel] = sOut[pixel*33 + plane];
    }
}

extern "C" void kernel_launch(void* const* d_in, const int* in_sizes, int n_in,
                              void* d_out, int out_size, void* d_ws, size_t ws_size,
                              hipStream_t stream)
{
    (void)in_sizes; (void)n_in; (void)out_size; (void)ws_size;
    const float* feat   = (const float*)d_in[0];
    const float* depths = (const float*)d_in[1];
    const float* K      = (const float*)d_in[2];
    const float* E      = (const float*)d_in[3];
    const float* w0     = (const float*)d_in[4];
    const float* b0     = (const float*)d_in[5];
    const float* w1     = (const float*)d_in[6];
    const float* b1     = (const float*)d_in[7];
    const float* w2     = (const float*)d_in[8];
    const float* b2     = (const float*)d_in[9];
    float* out = (float*)d_out;
    unsigned short* featT = (unsigned short*)d_ws;   // (V-1, HW, C) f16 = 37.7 MB

    dim3 g(HWn/1024, Vn-1);
    transpose_kernel<<<g, 256, 0, stream>>>(feat, featT);
    gbinet_kernel<<<HWn/64, 256, 0, stream>>>(feat, depths, K, E,
                                              w0,b0,w1,b1,w2,b2, featT, out);
}

// Round 6
// 227.584 us; speedup vs baseline: 1.1406x; 1.1406x over previous
//
#include <hip/hip_runtime.h>
#include <math.h>

#define Vn 5
#define Cn 32
#define Hn 384
#define Wn 384
#define Dn 4
#define Gn 8
#define HWn (Hn*Wn)   // 147456

typedef _Float16 h2 __attribute__((ext_vector_type(2)));
typedef float    f2 __attribute__((ext_vector_type(2)));

__device__ __forceinline__ float fdot2h(h2 a, h2 b, float c){
#if __has_builtin(__builtin_amdgcn_fdot2)
    return __builtin_amdgcn_fdot2(a, b, c, false);
#else
    return (float)a.x*(float)b.x + (float)a.y*(float)b.y + c;
#endif
}
__device__ __forceinline__ unsigned int packh2(float a, float b){  // accurate pack (RNE)
    h2 h;
    h.x = (_Float16)a;
    h.y = (_Float16)b;
    return __builtin_bit_cast(unsigned int, h);
}
// packed fp32 helpers -> v_pk_fma_f32 / v_pk_max_f32 (exact same fma math per lane)
__device__ __forceinline__ f2 fma2(f2 a, f2 b, f2 c){ return __builtin_elementwise_fma(a, b, c); }
__device__ __forceinline__ f2 max2(f2 a, f2 b){ return __builtin_elementwise_max(a, b); }
__device__ __forceinline__ f2 splat2(float x){ f2 r; r.x = x; r.y = x; return r; }

// ---------- small 3x3 helpers (device) ----------
__device__ __forceinline__ void inv3(const float* m, float* o){
    float a=m[0],b=m[1],c=m[2],d=m[3],e=m[4],f=m[5],g=m[6],h=m[7],i=m[8];
    float A =  e*i - f*h;
    float B = -(d*i - f*g);
    float C =  d*h - e*g;
    float det = a*A + b*B + c*C;
    float r = 1.f/det;
    o[0] = A*r;            o[1] = -(b*i - c*h)*r;  o[2] =  (b*f - c*e)*r;
    o[3] = B*r;            o[4] =  (a*i - c*g)*r;  o[5] = -(a*f - c*d)*r;
    o[6] = C*r;            o[7] = -(a*h - b*g)*r;  o[8] =  (a*e - b*d)*r;
}
__device__ __forceinline__ void mm3(const float* a, const float* b, float* o){
    #pragma unroll
    for (int r=0;r<3;r++)
        #pragma unroll
        for (int c=0;c<3;c++)
            o[r*3+c] = a[r*3+0]*b[0*3+c] + a[r*3+1]*b[1*3+c] + a[r*3+2]*b[2*3+c];
}
__device__ __forceinline__ void mv3(const float* a, const float* v, float* o){
    #pragma unroll
    for (int r=0;r<3;r++)
        o[r] = a[r*3+0]*v[0] + a[r*3+1]*v[1] + a[r*3+2]*v[2];
}

// ---------- transpose+convert (C,H,W) fp32 -> (H*W, C) f16 ----------
// R6: instruction-contiguous on BOTH sides via LDS exchange.
// R5 post-mortem on the LDS-free version: thread t stored 16B chunks at
// 256B stride -> each wave store-instr touched 64 lines with 32B/line
// (4x line redundancy, partial-line L2 writes). Here: 128 threads x 4 px;
// float4 loads (1KB/wave-instr); pack; stage 256B/thread to owner-linear
// padded LDS ([t][17] u4, ~8-way banks, volume ~1us total); barrier; lane l
// stores the chunk at global offset k*2048 + t*16 -> 1KB contiguous per
// wave store instruction, full-line writes.
__global__ __launch_bounds__(128)
void transpose_kernel(const float* __restrict__ feat, unsigned short* __restrict__ featT){
    __shared__ uint4 lds[128*17];                           // 34KB, +1 u4 pad/thread
    const int s  = blockIdx.y;                              // 0..3 -> view s+1
    const int P0 = blockIdx.x * 512;
    const int t  = threadIdx.x;
    const float* src = feat + (size_t)(s+1)*Cn*HWn + P0 + 4*t;
    unsigned int outw[4][16];
    #pragma unroll
    for (int c=0; c<Cn; c+=2){
        const float4 a = *(const float4*)(src + (size_t)c*HWn);
        const float4 b = *(const float4*)(src + (size_t)(c+1)*HWn);
        outw[0][c>>1] = packh2(a.x, b.x);
        outw[1][c>>1] = packh2(a.y, b.y);
        outw[2][c>>1] = packh2(a.z, b.z);
        outw[3][c>>1] = packh2(a.w, b.w);
    }
    // owner-linear: thread t's 16 chunks (px-major, then quarter) at [t*17 + i]
    #pragma unroll
    for (int p=0;p<4;p++)
        #pragma unroll
        for (int j=0;j<4;j++){
            uint4 o;
            o.x = outw[p][4*j+0];
            o.y = outw[p][4*j+1];
            o.z = outw[p][4*j+2];
            o.w = outw[p][4*j+3];
            lds[t*17 + p*4 + j] = o;
        }
    __syncthreads();
    // logical chunk c (= px_local*4 + quarter) lives at lds[(c>>4)*17 + (c&15)]
    unsigned short* dstb = featT + ((size_t)s*HWn + P0)*Cn;
    #pragma unroll
    for (int k=0;k<16;k++){
        const int c = k*128 + t;
        const uint4 v = lds[(c>>4)*17 + (c&15)];
        *(uint4*)(dstb + (size_t)c*8) = v;
    }
}

// one group (4 ch = 2 half2): two v_dot2_f32_f16 + one fma into sg[g]
#define DOTG(uA, uB, g, WV)                                                    \
    {                                                                          \
        const h2 pa = __builtin_bit_cast(h2, (uA));                            \
        const h2 pb = __builtin_bit_cast(h2, (uB));                            \
        const float dt = fdot2h(pa, r2[2*(g)], fdot2h(pb, r2[2*(g)+1], 0.f));  \
        sg[(g)] = fmaf((WV), dt, sg[(g)]);                                     \
    }

// guarded bilinear tap: loads only if weight nonzero, immediate consume.
// R2 POST-MORTEM: batching all 16 uint4 loads of a depth (branchless) raised
// VGPR 76->128, cut resident waves, and SLOWED 85->129us with identical
// absolute VALU-busy time. This kernel is TLP-limited: keep VGPR low
// (guarded per-tap load->use) and let wave interleaving hide latency.
// R5 POST-MORTEM: quarter-lane coalescing (16B/lane, 4 lanes/record) cut
// lines-per-instr ~4x but added shuffle-transpose VALU (+15us) and a 4x
// longer chain -> 94us. The 78us point is a balanced VALU/L1/latency wall;
// this guarded 64B-record structure is the local optimum.
__device__ __forceinline__ void tap_f16(const unsigned short* __restrict__ vbase,
                                        int xc, int yc, float w,
                                        const h2* r2, float* sg)
{
    if (w != 0.f){
        const uint4* p = (const uint4*)(vbase + ((size_t)yc*Wn + xc)*Cn);
        const uint4 q0 = p[0];
        const uint4 q1 = p[1];
        const uint4 q2 = p[2];
        const uint4 q3 = p[3];
        DOTG(q0.x, q0.y, 0, w)
        DOTG(q0.z, q0.w, 1, w)
        DOTG(q1.x, q1.y, 2, w)
        DOTG(q1.z, q1.w, 3, w)
        DOTG(q2.x, q2.y, 4, w)
        DOTG(q2.z, q2.w, 5, w)
        DOTG(q3.x, q3.y, 6, w)
        DOTG(q3.z, q3.w, 7, w)
    }
}

// ---------- fused main kernel (R4 structure, best measured: 78.1us) ----------
// One thread per (pixel, view, depth-half). Block = 256 threads =
// 32 pixels x 8 lanes; lane sub = s*2 + h. Each thread: 2 depths x 4 taps,
// packed-f2 MLP pass, shfl_xor(1) folds depth-half maxlog, shfl_xor(2)/(4)
// view reduction. NOTE: register arrays only with compile-time indices (SROA).
__global__ __launch_bounds__(256, 2)
void gbinet_kernel(const float* __restrict__ feat,
                   const float* __restrict__ depths,
                   const float* __restrict__ Kin,
                   const float* __restrict__ Ein,
                   const float* __restrict__ w0, const float* __restrict__ b0,
                   const float* __restrict__ w1, const float* __restrict__ b1,
                   const float* __restrict__ w2, const float* __restrict__ b2,
                   const unsigned short* __restrict__ featT,
                   float* __restrict__ out)
{
    __shared__ float sW0[128], sW1[128], sB0[16], sB1[8], sW2[8], sB2s[1];
    __shared__ float sM[48];            // per source view: A[9] + c[3]
    __shared__ float sRef[32*33];       // 32 pixels x 32 ref channels (pad 33)
    __shared__ float sDep[4*33];        // 4 depth planes x 32 pixels (pad 33)
    __shared__ float sOut[32*33];       // 32 pixels x 32 outputs (pad 33)
    const int t = threadIdx.x;
    if (t < 128){ sW0[t] = w0[t]; sW1[t] = w1[t]; }
    if (t < 16) sB0[t] = b0[t];
    if (t < 8){ sB1[t] = b1[t]; sW2[t] = w2[t]; }

    // XCD swizzle: round-robin dispatch -> each XCD gets a contiguous
    // 576-block (48-row) strip; featT tap neighborhoods stay in its L2.
    const int bid = blockIdx.x;
    const int sid = (bid & 7) * (HWn/32/8) + (bid >> 3);
    const int blockBase = sid * 32;

    // cooperative coalesced stage of ref (view0 fp32) and depths for 32 pixels
    {
        const float* srcR = feat + blockBase;
        #pragma unroll
        for (int k=0;k<4;k++){
            const int i  = k*256 + t;
            const int c  = i >> 5;
            const int px = i & 31;
            sRef[px*33 + c] = srcR[(size_t)c*HWn + px];
        }
        if (t < 128){
            const int dp = t >> 5;      // 0..3
            const int px = t & 31;
            sDep[dp*33 + px] = depths[(size_t)dp*HWn + blockBase + px];
        }
    }

    // Projection-chain setup, 4-way lane-parallel (one lane per source view).
    if (t < 4){
        float K0inv[9]; inv3(Kin, K0inv);
        float R0[9], t0[3];
        #pragma unroll
        for (int r=0;r<3;r++){
            #pragma unroll
            for (int c=0;c<3;c++) R0[r*3+c] = Ein[r*4+c];
            t0[r] = Ein[r*4+3];
        }
        float R0inv[9]; inv3(R0, R0inv);
        float M0[9]; mm3(R0inv, K0inv, M0);
        float Rt0[3]; mv3(R0inv, t0, Rt0);
        const int sv = t + 1;
        const float* Ks = Kin + sv*9;
        const float* Es = Ein + sv*12;
        float Rs[9], ts[3];
        #pragma unroll
        for (int r=0;r<3;r++){
            #pragma unroll
            for (int c=0;c<3;c++) Rs[r*3+c] = Es[r*4+c];
            ts[r] = Es[r*4+3];
        }
        float T1[9]; mm3(Rs, M0, T1);
        float A[9];  mm3(Ks, T1, A);
        float Rr[3]; mv3(Rs, Rt0, Rr);
        float tv[3] = { ts[0]-Rr[0], ts[1]-Rr[1], ts[2]-Rr[2] };
        float cv[3]; mv3(Ks, tv, cv);
        float* dm = &sM[t*12];
        #pragma unroll
        for (int i=0;i<9;i++) dm[i] = A[i];
        #pragma unroll
        for (int i=0;i<3;i++) dm[9+i] = cv[i];
    }
    if (t == 4) sB2s[0] = b2[0];
    __syncthreads();

    const int pixLocal = t >> 3;        // 0..31
    const int sub      = t & 7;
    const int s        = sub >> 1;      // source view index (0..3 -> view s+1)
    const int hh       = sub & 1;       // depth-half: depths {2h, 2h+1}
    const int pix      = blockBase + pixLocal;
    const float xg = (float)(pix % Wn) + 0.5f;
    const float yg = (float)(pix / Wn) + 0.5f;

    // ref as 16 packed half2 (f16 precision > bf16 for N(0,1) data)
    h2 r2[16];
    #pragma unroll
    for (int k=0;k<16;k++){
        r2[k].x = (_Float16)sRef[pixLocal*33 + 2*k];
        r2[k].y = (_Float16)sRef[pixLocal*33 + 2*k+1];
    }
    float dep[2];
    #pragma unroll
    for (int d=0;d<2;d++) dep[d] = sDep[(2*hh + d)*33 + pixLocal];

    const float* M = &sM[s*12];
    const float bx = M[0]*xg + M[1]*yg + M[2];
    const float by = M[3]*xg + M[4]*yg + M[5];
    const float bz = M[6]*xg + M[7]*yg + M[8];
    const float cx = M[9], cy = M[10], cz = M[11];
    const unsigned short* vbase = featT + (size_t)s*HWn*Cn;

    float sim[Gn][2];
    #pragma unroll
    for (int d=0;d<2;d++){
        const float dd = dep[d];
        const float ux = fmaf(bx, dd, cx);
        const float uy = fmaf(by, dd, cy);
        const float uz = fmaf(bz, dd, cz) + 1e-9f;
        const float rz = 1.f/uz;
        const float px = ux*rz, py = uy*rz;
        const float x0 = floorf(px), y0 = floorf(py);
        const float wx1 = px - x0, wy1 = py - y0;
        const float wx0 = 1.f - wx1, wy0 = 1.f - wy1;
        const bool vx0 = (x0 >= 0.f)     && (x0 <= (float)(Wn-1));
        const bool vx1 = (x0 >= -1.f)    && (x0 <= (float)(Wn-2));
        const bool vy0 = (y0 >= 0.f)     && (y0 <= (float)(Hn-1));
        const bool vy1 = (y0 >= -1.f)    && (y0 <= (float)(Hn-2));
        // fold the 1/4 group-mean into the tap weights
        const float w00 = (vx0&&vy0) ? 0.25f*wx0*wy0 : 0.f;
        const float w10 = (vx1&&vy0) ? 0.25f*wx1*wy0 : 0.f;
        const float w01 = (vx0&&vy1) ? 0.25f*wx0*wy1 : 0.f;
        const float w11 = (vx1&&vy1) ? 0.25f*wx1*wy1 : 0.f;
        // clamped integer coords (always safe to load)
        const int xi0 = (int)fminf(fmaxf(x0,     0.f), (float)(Wn-1));
        const int xi1 = (int)fminf(fmaxf(x0+1.f, 0.f), (float)(Wn-1));
        const int yi0 = (int)fminf(fmaxf(y0,     0.f), (float)(Hn-1));
        const int yi1 = (int)fminf(fmaxf(y0+1.f, 0.f), (float)(Hn-1));

        float sg[Gn];
        #pragma unroll
        for (int g=0; g<Gn; g++) sg[g] = 0.f;
        tap_f16(vbase, xi0, yi0, w00, r2, sg);
        tap_f16(vbase, xi1, yi0, w10, r2, sg);
        tap_f16(vbase, xi0, yi1, w01, r2, sg);
        tap_f16(vbase, xi1, yi1, w11, r2, sg);
        #pragma unroll
        for (int g=0; g<Gn; g++) sim[g][d] = sg[g];
    }

    // pixelwise net on this lane's depth pair via packed fp32
    // (v_pk_fma_f32 / v_pk_max_f32): identical fma chain -> bit-identical.
    // max(sigmoid) == sigmoid(max logit).
    f2 sv[Gn];
    #pragma unroll
    for (int g=0; g<Gn; g++){ sv[g].x = sim[g][0]; sv[g].y = sim[g][1]; }
    f2 hreg[16];
    #pragma unroll
    for (int o=0;o<16;o++){
        f2 a = splat2(sB0[o]);
        #pragma unroll
        for (int g=0; g<Gn; g++)
            a = fma2(splat2(sW0[o*Gn+g]), sv[g], a);
        hreg[o] = max2(a, splat2(0.f));
    }
    f2 lg = splat2(sB2s[0]);
    #pragma unroll
    for (int o=0;o<8;o++){
        f2 a = splat2(sB1[o]);
        #pragma unroll
        for (int i=0;i<16;i++)
            a = fma2(splat2(sW1[o*16+i]), hreg[i], a);
        lg = fma2(splat2(sW2[o]), max2(a, splat2(0.f)), lg);
    }
    float mx = fmaxf(lg.x, lg.y);
    const float maxlog = fmaxf(mx, __shfl_xor(mx, 1));   // fold depth halves
    const float vw = 1.f/(1.f + __expf(-maxlog));

    // scale by vw, butterfly-reduce across the 4 view lanes (bits 1-2)
    float wsum = vw;
    wsum += __shfl_xor(wsum, 2);
    wsum += __shfl_xor(wsum, 4);
    #pragma unroll
    for (int g=0;g<Gn;g++)
        #pragma unroll
        for (int d=0;d<2;d++){
            float v = sim[g][d]*vw;
            v += __shfl_xor(v, 2);
            v += __shfl_xor(v, 4);
            sim[g][d] = v;
        }

    if (s == 0){                        // sub 0 (depths 0,1) and sub 1 (2,3)
        const float invw = 1.f/wsum;
        #pragma unroll
        for (int g=0;g<Gn;g++)
            #pragma unroll
            for (int d=0;d<2;d++)
                sOut[pixLocal*33 + g*Dn + 2*hh + d] = sim[g][d]*invw;
    }
    __syncthreads();

    // coalesced write-out: 32 planes x 32 pixels
    float* oBase = out + blockBase;
    #pragma unroll
    for (int k=0;k<4;k++){
        const int e     = k*256 + t;
        const int plane = e >> 5;
        const int pixel = e & 31;
        oBase[(size_t)plane*HWn + pixel] = sOut[pixel*33 + plane];
    }
}

extern "C" void kernel_launch(void* const* d_in, const int* in_sizes, int n_in,
                              void* d_out, int out_size, void* d_ws, size_t ws_size,
                              hipStream_t stream)
{
    (void)in_sizes; (void)n_in; (void)out_size; (void)ws_size;
    const float* feat   = (const float*)d_in[0];
    const float* depths = (const float*)d_in[1];
    const float* K      = (const float*)d_in[2];
    const float* E      = (const float*)d_in[3];
    const float* w0     = (const float*)d_in[4];
    const float* b0     = (const float*)d_in[5];
    const float* w1     = (const float*)d_in[6];
    const float* b1     = (const float*)d_in[7];
    const float* w2     = (const float*)d_in[8];
    const float* b2     = (const float*)d_in[9];
    float* out = (float*)d_out;
    unsigned short* featT = (unsigned short*)d_ws;   // (V-1, HW, C) f16 = 37.7 MB

    dim3 g(HWn/512, Vn-1);
    transpose_kernel<<<g, 128, 0, stream>>>(feat, featT);
    gbinet_kernel<<<HWn/32, 256, 0, stream>>>(feat, depths, K, E,
                                              w0,b0,w1,b1,w2,b2, featT, out);
}

// Round 7
// 226.272 us; speedup vs baseline: 1.1472x; 1.0058x over previous
//
#include <hip/hip_runtime.h>
#include <math.h>

#define Vn 5
#define Cn 32
#define Hn 384
#define Wn 384
#define Dn 4
#define Gn 8
#define HWn (Hn*Wn)   // 147456

typedef _Float16 h2 __attribute__((ext_vector_type(2)));
typedef float    f2 __attribute__((ext_vector_type(2)));

__device__ __forceinline__ float fdot2h(h2 a, h2 b, float c){
#if __has_builtin(__builtin_amdgcn_fdot2)
    return __builtin_amdgcn_fdot2(a, b, c, false);
#else
    return (float)a.x*(float)b.x + (float)a.y*(float)b.y + c;
#endif
}
__device__ __forceinline__ unsigned int packh2(float a, float b){  // accurate pack (RNE)
    h2 h;
    h.x = (_Float16)a;
    h.y = (_Float16)b;
    return __builtin_bit_cast(unsigned int, h);
}
// packed fp32 helpers -> v_pk_fma_f32 / v_pk_max_f32 (exact same fma math per lane)
__device__ __forceinline__ f2 fma2(f2 a, f2 b, f2 c){ return __builtin_elementwise_fma(a, b, c); }
__device__ __forceinline__ f2 max2(f2 a, f2 b){ return __builtin_elementwise_max(a, b); }
__device__ __forceinline__ f2 splat2(float x){ f2 r; r.x = x; r.y = x; return r; }

// ---------- small 3x3 helpers (device) ----------
__device__ __forceinline__ void inv3(const float* m, float* o){
    float a=m[0],b=m[1],c=m[2],d=m[3],e=m[4],f=m[5],g=m[6],h=m[7],i=m[8];
    float A =  e*i - f*h;
    float B = -(d*i - f*g);
    float C =  d*h - e*g;
    float det = a*A + b*B + c*C;
    float r = 1.f/det;
    o[0] = A*r;            o[1] = -(b*i - c*h)*r;  o[2] =  (b*f - c*e)*r;
    o[3] = B*r;            o[4] =  (a*i - c*g)*r;  o[5] = -(a*f - c*d)*r;
    o[6] = C*r;            o[7] = -(a*h - b*g)*r;  o[8] =  (a*e - b*d)*r;
}
__device__ __forceinline__ void mm3(const float* a, const float* b, float* o){
    #pragma unroll
    for (int r=0;r<3;r++)
        #pragma unroll
        for (int c=0;c<3;c++)
            o[r*3+c] = a[r*3+0]*b[0*3+c] + a[r*3+1]*b[1*3+c] + a[r*3+2]*b[2*3+c];
}
__device__ __forceinline__ void mv3(const float* a, const float* v, float* o){
    #pragma unroll
    for (int r=0;r<3;r++)
        o[r] = a[r*3+0]*v[0] + a[r*3+1]*v[1] + a[r*3+2]*v[2];
}

// ---------- transpose+convert (C,H,W) fp32 -> (H*W, C) f16 ----------
// R7: same instruction-contiguous store structure as R6 (which cut ~14us),
// but 2 px/thread instead of 4: LDS 34->18KB, grid 1152->2304 blocks ->
// occupancy cap rises from ~4 blocks/CU (8 waves) to ~8 blocks/CU
// (16 waves). Pure streaming kernel at 8 waves/CU was latency-exposed;
// 2x waves should push it toward the 113MB/6.3TBps = 18us floor.
// Loads: float2 = 8B/lane = 512B/wave-instr (G13 sweet spot). Stores:
// lane-contiguous 16B chunks = 1KB/wave-instr, full-line writes.
__global__ __launch_bounds__(128)
void transpose_kernel(const float* __restrict__ feat, unsigned short* __restrict__ featT){
    __shared__ uint4 lds[128*9];                            // 18KB: 8 chunks + 1 pad/thread
    const int s  = blockIdx.y;                              // 0..3 -> view s+1
    const int P0 = blockIdx.x * 256;
    const int t  = threadIdx.x;
    const float* src = feat + (size_t)(s+1)*Cn*HWn + P0 + 2*t;
    unsigned int outw[2][16];
    #pragma unroll
    for (int c=0; c<Cn; c+=2){
        const f2 a = *(const f2*)(src + (size_t)c*HWn);
        const f2 b = *(const f2*)(src + (size_t)(c+1)*HWn);
        outw[0][c>>1] = packh2(a.x, b.x);
        outw[1][c>>1] = packh2(a.y, b.y);
    }
    // owner-linear: thread t's 8 chunks (px-major, then quarter) at [t*9 + i];
    // lane stride 9 x 16B -> consecutive lanes walk consecutive 16B bank
    // groups (stride 9 mod 8 == 1): b128 baseline, no extra conflicts.
    #pragma unroll
    for (int p=0;p<2;p++)
        #pragma unroll
        for (int j=0;j<4;j++){
            uint4 o;
            o.x = outw[p][4*j+0];
            o.y = outw[p][4*j+1];
            o.z = outw[p][4*j+2];
            o.w = outw[p][4*j+3];
            lds[t*9 + p*4 + j] = o;
        }
    __syncthreads();
    // logical chunk c (= px_local*4 + quarter) lives at lds[(c>>3)*9 + (c&7)]
    unsigned short* dstb = featT + ((size_t)s*HWn + P0)*Cn;
    #pragma unroll
    for (int k=0;k<8;k++){
        const int c = k*128 + t;
        const uint4 v = lds[(c>>3)*9 + (c&7)];
        *(uint4*)(dstb + (size_t)c*8) = v;
    }
}

// one group (4 ch = 2 half2): two v_dot2_f32_f16 + one fma into sg[g]
#define DOTG(uA, uB, g, WV)                                                    \
    {                                                                          \
        const h2 pa = __builtin_bit_cast(h2, (uA));                            \
        const h2 pb = __builtin_bit_cast(h2, (uB));                            \
        const float dt = fdot2h(pa, r2[2*(g)], fdot2h(pb, r2[2*(g)+1], 0.f));  \
        sg[(g)] = fmaf((WV), dt, sg[(g)]);                                     \
    }

// guarded bilinear tap: loads only if weight nonzero, immediate consume.
// R2 POST-MORTEM: batching all 16 uint4 loads of a depth (branchless) raised
// VGPR 76->128, cut resident waves, and SLOWED 85->129us with identical
// absolute VALU-busy time. This kernel is TLP-limited: keep VGPR low
// (guarded per-tap load->use) and let wave interleaving hide latency.
// R5 POST-MORTEM: quarter-lane coalescing (16B/lane, 4 lanes/record) cut
// lines-per-instr ~4x but added shuffle-transpose VALU (+15us) and a 4x
// longer chain -> 94us. The 78us point is a balanced VALU/L1/latency wall;
// this guarded 64B-record structure is the local optimum.
__device__ __forceinline__ void tap_f16(const unsigned short* __restrict__ vbase,
                                        int xc, int yc, float w,
                                        const h2* r2, float* sg)
{
    if (w != 0.f){
        const uint4* p = (const uint4*)(vbase + ((size_t)yc*Wn + xc)*Cn);
        const uint4 q0 = p[0];
        const uint4 q1 = p[1];
        const uint4 q2 = p[2];
        const uint4 q3 = p[3];
        DOTG(q0.x, q0.y, 0, w)
        DOTG(q0.z, q0.w, 1, w)
        DOTG(q1.x, q1.y, 2, w)
        DOTG(q1.z, q1.w, 3, w)
        DOTG(q2.x, q2.y, 4, w)
        DOTG(q2.z, q2.w, 5, w)
        DOTG(q3.x, q3.y, 6, w)
        DOTG(q3.z, q3.w, 7, w)
    }
}

// ---------- fused main kernel (R4 structure, best measured: 77.4us) ----------
// One thread per (pixel, view, depth-half). Block = 256 threads =
// 32 pixels x 8 lanes; lane sub = s*2 + h. Each thread: 2 depths x 4 taps,
// packed-f2 MLP pass, shfl_xor(1) folds depth-half maxlog, shfl_xor(2)/(4)
// view reduction. NOTE: register arrays only with compile-time indices (SROA).
__global__ __launch_bounds__(256, 2)
void gbinet_kernel(const float* __restrict__ feat,
                   const float* __restrict__ depths,
                   const float* __restrict__ Kin,
                   const float* __restrict__ Ein,
                   const float* __restrict__ w0, const float* __restrict__ b0,
                   const float* __restrict__ w1, const float* __restrict__ b1,
                   const float* __restrict__ w2, const float* __restrict__ b2,
                   const unsigned short* __restrict__ featT,
                   float* __restrict__ out)
{
    __shared__ float sW0[128], sW1[128], sB0[16], sB1[8], sW2[8], sB2s[1];
    __shared__ float sM[48];            // per source view: A[9] + c[3]
    __shared__ float sRef[32*33];       // 32 pixels x 32 ref channels (pad 33)
    __shared__ float sDep[4*33];        // 4 depth planes x 32 pixels (pad 33)
    __shared__ float sOut[32*33];       // 32 pixels x 32 outputs (pad 33)
    const int t = threadIdx.x;
    if (t < 128){ sW0[t] = w0[t]; sW1[t] = w1[t]; }
    if (t < 16) sB0[t] = b0[t];
    if (t < 8){ sB1[t] = b1[t]; sW2[t] = w2[t]; }

    // XCD swizzle: round-robin dispatch -> each XCD gets a contiguous
    // 576-block (48-row) strip; featT tap neighborhoods stay in its L2.
    const int bid = blockIdx.x;
    const int sid = (bid & 7) * (HWn/32/8) + (bid >> 3);
    const int blockBase = sid * 32;

    // cooperative coalesced stage of ref (view0 fp32) and depths for 32 pixels
    {
        const float* srcR = feat + blockBase;
        #pragma unroll
        for (int k=0;k<4;k++){
            const int i  = k*256 + t;
            const int c  = i >> 5;
            const int px = i & 31;
            sRef[px*33 + c] = srcR[(size_t)c*HWn + px];
        }
        if (t < 128){
            const int dp = t >> 5;      // 0..3
            const int px = t & 31;
            sDep[dp*33 + px] = depths[(size_t)dp*HWn + blockBase + px];
        }
    }

    // Projection-chain setup, 4-way lane-parallel (one lane per source view).
    if (t < 4){
        float K0inv[9]; inv3(Kin, K0inv);
        float R0[9], t0[3];
        #pragma unroll
        for (int r=0;r<3;r++){
            #pragma unroll
            for (int c=0;c<3;c++) R0[r*3+c] = Ein[r*4+c];
            t0[r] = Ein[r*4+3];
        }
        float R0inv[9]; inv3(R0, R0inv);
        float M0[9]; mm3(R0inv, K0inv, M0);
        float Rt0[3]; mv3(R0inv, t0, Rt0);
        const int sv = t + 1;
        const float* Ks = Kin + sv*9;
        const float* Es = Ein + sv*12;
        float Rs[9], ts[3];
        #pragma unroll
        for (int r=0;r<3;r++){
            #pragma unroll
            for (int c=0;c<3;c++) Rs[r*3+c] = Es[r*4+c];
            ts[r] = Es[r*4+3];
        }
        float T1[9]; mm3(Rs, M0, T1);
        float A[9];  mm3(Ks, T1, A);
        float Rr[3]; mv3(Rs, Rt0, Rr);
        float tv[3] = { ts[0]-Rr[0], ts[1]-Rr[1], ts[2]-Rr[2] };
        float cv[3]; mv3(Ks, tv, cv);
        float* dm = &sM[t*12];
        #pragma unroll
        for (int i=0;i<9;i++) dm[i] = A[i];
        #pragma unroll
        for (int i=0;i<3;i++) dm[9+i] = cv[i];
    }
    if (t == 4) sB2s[0] = b2[0];
    __syncthreads();

    const int pixLocal = t >> 3;        // 0..31
    const int sub      = t & 7;
    const int s        = sub >> 1;      // source view index (0..3 -> view s+1)
    const int hh       = sub & 1;       // depth-half: depths {2h, 2h+1}
    const int pix      = blockBase + pixLocal;
    const float xg = (float)(pix % Wn) + 0.5f;
    const float yg = (float)(pix / Wn) + 0.5f;

    // ref as 16 packed half2 (f16 precision > bf16 for N(0,1) data)
    h2 r2[16];
    #pragma unroll
    for (int k=0;k<16;k++){
        r2[k].x = (_Float16)sRef[pixLocal*33 + 2*k];
        r2[k].y = (_Float16)sRef[pixLocal*33 + 2*k+1];
    }
    float dep[2];
    #pragma unroll
    for (int d=0;d<2;d++) dep[d] = sDep[(2*hh + d)*33 + pixLocal];

    const float* M = &sM[s*12];
    const float bx = M[0]*xg + M[1]*yg + M[2];
    const float by = M[3]*xg + M[4]*yg + M[5];
    const float bz = M[6]*xg + M[7]*yg + M[8];
    const float cx = M[9], cy = M[10], cz = M[11];
    const unsigned short* vbase = featT + (size_t)s*HWn*Cn;

    float sim[Gn][2];
    #pragma unroll
    for (int d=0;d<2;d++){
        const float dd = dep[d];
        const float ux = fmaf(bx, dd, cx);
        const float uy = fmaf(by, dd, cy);
        const float uz = fmaf(bz, dd, cz) + 1e-9f;
        const float rz = 1.f/uz;
        const float px = ux*rz, py = uy*rz;
        const float x0 = floorf(px), y0 = floorf(py);
        const float wx1 = px - x0, wy1 = py - y0;
        const float wx0 = 1.f - wx1, wy0 = 1.f - wy1;
        const bool vx0 = (x0 >= 0.f)     && (x0 <= (float)(Wn-1));
        const bool vx1 = (x0 >= -1.f)    && (x0 <= (float)(Wn-2));
        const bool vy0 = (y0 >= 0.f)     && (y0 <= (float)(Hn-1));
        const bool vy1 = (y0 >= -1.f)    && (y0 <= (float)(Hn-2));
        // fold the 1/4 group-mean into the tap weights
        const float w00 = (vx0&&vy0) ? 0.25f*wx0*wy0 : 0.f;
        const float w10 = (vx1&&vy0) ? 0.25f*wx1*wy0 : 0.f;
        const float w01 = (vx0&&vy1) ? 0.25f*wx0*wy1 : 0.f;
        const float w11 = (vx1&&vy1) ? 0.25f*wx1*wy1 : 0.f;
        // clamped integer coords (always safe to load)
        const int xi0 = (int)fminf(fmaxf(x0,     0.f), (float)(Wn-1));
        const int xi1 = (int)fminf(fmaxf(x0+1.f, 0.f), (float)(Wn-1));
        const int yi0 = (int)fminf(fmaxf(y0,     0.f), (float)(Hn-1));
        const int yi1 = (int)fminf(fmaxf(y0+1.f, 0.f), (float)(Hn-1));

        float sg[Gn];
        #pragma unroll
        for (int g=0; g<Gn; g++) sg[g] = 0.f;
        tap_f16(vbase, xi0, yi0, w00, r2, sg);
        tap_f16(vbase, xi1, yi0, w10, r2, sg);
        tap_f16(vbase, xi0, yi1, w01, r2, sg);
        tap_f16(vbase, xi1, yi1, w11, r2, sg);
        #pragma unroll
        for (int g=0; g<Gn; g++) sim[g][d] = sg[g];
    }

    // pixelwise net on this lane's depth pair via packed fp32
    // (v_pk_fma_f32 / v_pk_max_f32): identical fma chain -> bit-identical.
    // max(sigmoid) == sigmoid(max logit).
    f2 sv[Gn];
    #pragma unroll
    for (int g=0; g<Gn; g++){ sv[g].x = sim[g][0]; sv[g].y = sim[g][1]; }
    f2 hreg[16];
    #pragma unroll
    for (int o=0;o<16;o++){
        f2 a = splat2(sB0[o]);
        #pragma unroll
        for (int g=0; g<Gn; g++)
            a = fma2(splat2(sW0[o*Gn+g]), sv[g], a);
        hreg[o] = max2(a, splat2(0.f));
    }
    f2 lg = splat2(sB2s[0]);
    #pragma unroll
    for (int o=0;o<8;o++){
        f2 a = splat2(sB1[o]);
        #pragma unroll
        for (int i=0;i<16;i++)
            a = fma2(splat2(sW1[o*16+i]), hreg[i], a);
        lg = fma2(splat2(sW2[o]), max2(a, splat2(0.f)), lg);
    }
    float mx = fmaxf(lg.x, lg.y);
    const float maxlog = fmaxf(mx, __shfl_xor(mx, 1));   // fold depth halves
    const float vw = 1.f/(1.f + __expf(-maxlog));

    // scale by vw, butterfly-reduce across the 4 view lanes (bits 1-2)
    float wsum = vw;
    wsum += __shfl_xor(wsum, 2);
    wsum += __shfl_xor(wsum, 4);
    #pragma unroll
    for (int g=0;g<Gn;g++)
        #pragma unroll
        for (int d=0;d<2;d++){
            float v = sim[g][d]*vw;
            v += __shfl_xor(v, 2);
            v += __shfl_xor(v, 4);
            sim[g][d] = v;
        }

    if (s == 0){                        // sub 0 (depths 0,1) and sub 1 (2,3)
        const float invw = 1.f/wsum;
        #pragma unroll
        for (int g=0;g<Gn;g++)
            #pragma unroll
            for (int d=0;d<2;d++)
                sOut[pixLocal*33 + g*Dn + 2*hh + d] = sim[g][d]*invw;
    }
    __syncthreads();

    // coalesced write-out: 32 planes x 32 pixels
    float* oBase = out + blockBase;
    #pragma unroll
    for (int k=0;k<4;k++){
        const int e     = k*256 + t;
        const int plane = e >> 5;
        const int pixel = e & 31;
        oBase[(size_t)plane*HWn + pixel] = sOut[pixel*33 + plane];
    }
}

extern "C" void kernel_launch(void* const* d_in, const int* in_sizes, int n_in,
                              void* d_out, int out_size, void* d_ws, size_t ws_size,
                              hipStream_t stream)
{
    (void)in_sizes; (void)n_in; (void)out_size; (void)ws_size;
    const float* feat   = (const float*)d_in[0];
    const float* depths = (const float*)d_in[1];
    const float* K      = (const float*)d_in[2];
    const float* E      = (const float*)d_in[3];
    const float* w0     = (const float*)d_in[4];
    const float* b0     = (const float*)d_in[5];
    const float* w1     = (const float*)d_in[6];
    const float* b1     = (const float*)d_in[7];
    const float* w2     = (const float*)d_in[8];
    const float* b2     = (const float*)d_in[9];
    float* out = (float*)d_out;
    unsigned short* featT = (unsigned short*)d_ws;   // (V-1, HW, C) f16 = 37.7 MB

    dim3 g(HWn/256, Vn-1);
    transpose_kernel<<<g, 128, 0, stream>>>(feat, featT);
    gbinet_kernel<<<HWn/32, 256, 0, stream>>>(feat, depths, K, E,
                                              w0,b0,w1,b1,w2,b2, featT, out);
}